// Round 17
// baseline (119.214 us; speedup 1.0000x reference)
//
#include <hip/hip_runtime.h>

// Problem constants: B=2, T=1024, E=1024, H=16, D=64
#define TT 1024
#define EE 1024

typedef __attribute__((ext_vector_type(8))) short short8;      // 8 bf16 MFMA frag
typedef __attribute__((ext_vector_type(4))) float floatx4;     // MFMA acc
typedef __attribute__((ext_vector_type(4))) unsigned short ushort4v;
typedef __attribute__((ext_vector_type(8))) unsigned short ushort8v;

static __device__ __forceinline__ unsigned short f2bf(float f) {
  union { float f; unsigned int u; } v; v.f = f;
  unsigned int u = v.u;
  u += 0x7FFFu + ((u >> 16) & 1u);  // RNE
  return (unsigned short)(u >> 16);
}
static __device__ __forceinline__ float bf2f(unsigned short u) {
  union { unsigned int i; float f; } v; v.i = ((unsigned int)u) << 16;
  return v.f;
}
static __device__ __forceinline__ void splitbf(float x, unsigned short& h,
                                               unsigned short& l) {
  h = f2bf(x);
  l = f2bf(x - bf2f(h));
}
// swizzled LDS access into a [rows][128B] bf16 tile, XOR bits 4-6 by row&7
static __device__ __forceinline__ unsigned short* lp(const unsigned short* t,
                                                     int row, int byte) {
  return (unsigned short*)((const char*)t + row * 128 + (byte ^ ((row & 7) << 4)));
}
static __device__ __forceinline__ short8 ldf(const unsigned short* t, int row,
                                             int byte) {
  return *(const short8*)((const char*)t + row * 128 + (byte ^ ((row & 7) << 4)));
}
// load 8 consecutive fp32 -> bf16 short8 fragment (in-register Wf conversion)
static __device__ __forceinline__ short8 ldwf(const float* p) {
  float4 a = *reinterpret_cast<const float4*>(p);
  float4 b = *reinterpret_cast<const float4*>(p + 4);
  ushort8v o;
  o[0] = f2bf(a.x); o[1] = f2bf(a.y); o[2] = f2bf(a.z); o[3] = f2bf(a.w);
  o[4] = f2bf(b.x); o[5] = f2bf(b.y); o[6] = f2bf(b.z); o[7] = f2bf(b.w);
  union { ushort8v u; short8 s; } cv;
  cv.u = o;
  return cv.s;
}

// ---------------------------------------------------------------------------
// Kernel B1' (fused prep + scores, 512 blocks):
//   chunk loop: stage x^T (hi/lo, transposed) -> Sxx via split-bf16 MFMA
//   (redundant x16 per bh — parallel & L2-local). ih==0 blocks emit xbf (=hi).
//   sx partials keyed by THREAD GROUP (r>>4), not staged row (bugfix vs R16).
//   Then: A1 = Wq@S, scores = A1@Wk^T (split-bf16) + bias -> softmax ->
//   M^T = WvT x w. XCD-aware decode (bh = blk&31).
// ---------------------------------------------------------------------------
__global__ __launch_bounds__(256) void kB1(const float* __restrict__ x,
                                           const float* __restrict__ Wq,
                                           const float* __restrict__ bq,
                                           const float* __restrict__ Wk,
                                           const float* __restrict__ bk,
                                           const float* __restrict__ Wv,
                                           const float* __restrict__ bv,
                                           unsigned short* __restrict__ Mtbf,
                                           unsigned short* __restrict__ xbf) {
  const int blk = blockIdx.x;
  const int bh = blk & 31, ih = blk >> 5;  // XCD-locality decode
  const int b = bh >> 4, h = bh & 15;
  const int r = threadIdx.x;
  const int w = r >> 6, l = r & 63;
  const int wm = w >> 1, wn = w & 1;
  const int lm = l & 15, lk = l >> 4;

  __shared__ unsigned short TSh[4096], TSl[4096];  // x^T chunks -> S hi/lo -> WvT, w
  __shared__ unsigned short TWh[4096], TWl[4096];  // Wq -> Wk (hi/lo)
  __shared__ unsigned short TAh[4096], TAl[4096];  // A1 hi/lo
  __shared__ float SC[64 * 68];                    // fp32 scores
  __shared__ float sxp[1024];                      // [16 thread-group][64 d]
  __shared__ float svec[64], qsv[64], ksv[64], bqv[64], bkv[64], bvv[64];

#pragma unroll
  for (int j = 0; j < 4; ++j) sxp[j * 256 + r] = 0.f;
  __syncthreads();

  // --- Sxx = x^T x via split-bf16 MFMA over 16 chunks of 64 t
  const int tg = r >> 4;            // thread group 0..15 (fixed per thread)
  const int d0s = (r & 15) * 4;     // fixed column group per thread
  floatx4 sacc[2][2] = {};
  const float* xb = x + (size_t)b * TT * EE + h * 64;
  for (int c = 0; c < 16; ++c) {
#pragma unroll
    for (int it = 0; it < 4; ++it) {
      int tl = it * 16 + tg;        // staged t-row within chunk (0..63)
      float4 v = *reinterpret_cast<const float4*>(
          &xb[(size_t)(c * 64 + tl) * EE + d0s]);
      float fv[4] = {v.x, v.y, v.z, v.w};
      unsigned short hi[4];
#pragma unroll
      for (int j = 0; j < 4; ++j) {
        unsigned short th, tlo;
        splitbf(fv[j], th, tlo);
        hi[j] = th;
        *lp(TSh, d0s + j, tl * 2) = th;   // transposed: [d][t]
        *lp(TSl, d0s + j, tl * 2) = tlo;
        sxp[tg * 64 + d0s + j] += fv[j];  // per-thread-owned slot (bugfix)
      }
      if (ih == 0) {
        ushort4v o;
        o[0] = hi[0]; o[1] = hi[1]; o[2] = hi[2]; o[3] = hi[3];
        *reinterpret_cast<ushort4v*>(
            &xbf[((size_t)bh * TT + c * 64 + tl) * 64 + d0s]) = o;
      }
    }
    __syncthreads();
    short8 Ah[2][2], Al[2][2], Bh[2][2], Bl[2][2];
#pragma unroll
    for (int mt = 0; mt < 2; ++mt)
#pragma unroll
      for (int ks = 0; ks < 2; ++ks) {
        Ah[mt][ks] = ldf(TSh, wm * 32 + mt * 16 + lm, ks * 64 + lk * 16);
        Al[mt][ks] = ldf(TSl, wm * 32 + mt * 16 + lm, ks * 64 + lk * 16);
        Bh[mt][ks] = ldf(TSh, wn * 32 + mt * 16 + lm, ks * 64 + lk * 16);
        Bl[mt][ks] = ldf(TSl, wn * 32 + mt * 16 + lm, ks * 64 + lk * 16);
      }
#pragma unroll
    for (int ks = 0; ks < 2; ++ks)
#pragma unroll
      for (int mt = 0; mt < 2; ++mt)
#pragma unroll
        for (int nt = 0; nt < 2; ++nt) {
          sacc[mt][nt] = __builtin_amdgcn_mfma_f32_16x16x32_bf16(Ah[mt][ks], Bh[nt][ks], sacc[mt][nt], 0, 0, 0);
          sacc[mt][nt] = __builtin_amdgcn_mfma_f32_16x16x32_bf16(Ah[mt][ks], Bl[nt][ks], sacc[mt][nt], 0, 0, 0);
          sacc[mt][nt] = __builtin_amdgcn_mfma_f32_16x16x32_bf16(Al[mt][ks], Bh[nt][ks], sacc[mt][nt], 0, 0, 0);
        }
    __syncthreads();
  }
  // write S (split hi/lo) into TSh/TSl; stage Wq into TW; svec + biases
#pragma unroll
  for (int mt = 0; mt < 2; ++mt)
#pragma unroll
    for (int nt = 0; nt < 2; ++nt)
#pragma unroll
      for (int q = 0; q < 4; ++q) {
        int p = wm * 32 + mt * 16 + lk * 4 + q;
        int dd = wn * 32 + nt * 16 + lm;
        unsigned short h2, l2;
        splitbf(sacc[mt][nt][q], h2, l2);
        *lp(TSh, p, dd * 2) = h2;
        *lp(TSl, p, dd * 2) = l2;
      }
#pragma unroll
  for (int it = 0; it < 4; ++it) {
    int idx = it * 1024 + r * 4;
    int row = idx >> 6, c0 = idx & 63;
    float4 vw = *(const float4*)&Wq[ih * 4096 + idx];
    float fw[4] = {vw.x, vw.y, vw.z, vw.w};
    ushort4v wh, wl;
#pragma unroll
    for (int j = 0; j < 4; ++j) {
      unsigned short th, tl2;
      splitbf(fw[j], th, tl2);
      wh[j] = th; wl[j] = tl2;
    }
    *(ushort4v*)lp(TWh, row, c0 * 2) = wh;
    *(ushort4v*)lp(TWl, row, c0 * 2) = wl;
  }
  if (r < 64) {
    float s = 0.f;
#pragma unroll
    for (int g = 0; g < 16; ++g) s += sxp[g * 64 + r];
    svec[r] = s;
    bqv[r] = bq[ih * 64 + r];
    bkv[r] = bk[ih * 64 + r];
    bvv[r] = bv[ih * 64 + r];
  }
  __syncthreads();

  // phase 1: A1 = Wq @ S (split-bf16)
  floatx4 a1[2][2] = {};
  {
    short8 Ah[2][2], Al[2][2], Bh[2][2], Bl[2][2];
#pragma unroll
    for (int mt = 0; mt < 2; ++mt)
#pragma unroll
      for (int ks = 0; ks < 2; ++ks) {
        Ah[mt][ks] = ldf(TWh, wm * 32 + mt * 16 + lm, ks * 64 + lk * 16);
        Al[mt][ks] = ldf(TWl, wm * 32 + mt * 16 + lm, ks * 64 + lk * 16);
        Bh[mt][ks] = ldf(TSh, wn * 32 + mt * 16 + lm, ks * 64 + lk * 16);
        Bl[mt][ks] = ldf(TSl, wn * 32 + mt * 16 + lm, ks * 64 + lk * 16);
      }
#pragma unroll
    for (int ks = 0; ks < 2; ++ks)
#pragma unroll
      for (int mt = 0; mt < 2; ++mt)
#pragma unroll
        for (int nt = 0; nt < 2; ++nt) {
          a1[mt][nt] = __builtin_amdgcn_mfma_f32_16x16x32_bf16(Ah[mt][ks], Bh[nt][ks], a1[mt][nt], 0, 0, 0);
          a1[mt][nt] = __builtin_amdgcn_mfma_f32_16x16x32_bf16(Ah[mt][ks], Bl[nt][ks], a1[mt][nt], 0, 0, 0);
          a1[mt][nt] = __builtin_amdgcn_mfma_f32_16x16x32_bf16(Al[mt][ks], Bh[nt][ks], a1[mt][nt], 0, 0, 0);
        }
  }
#pragma unroll
  for (int mt = 0; mt < 2; ++mt)
#pragma unroll
    for (int nt = 0; nt < 2; ++nt)
#pragma unroll
      for (int q = 0; q < 4; ++q) {
        int p = wm * 32 + mt * 16 + lk * 4 + q;
        int dd = wn * 32 + nt * 16 + lm;
        unsigned short h2, lo2;
        splitbf(a1[mt][nt][q], h2, lo2);
        *lp(TAh, p, dd * 2) = h2;
        *lp(TAl, p, dd * 2) = lo2;
      }
  {  // qs = Wq @ s_x
    int p = r >> 2, dc = (r & 3) * 16;
    float s = 0.f;
#pragma unroll
    for (int j = 0; j < 16; ++j) {
      int d = dc + j;
      s += (bf2f(*lp(TWh, p, d * 2)) + bf2f(*lp(TWl, p, d * 2))) * svec[d];
    }
    s += __shfl_xor(s, 1);
    s += __shfl_xor(s, 2);
    if ((r & 3) == 0) qsv[p] = s;
  }
  __syncthreads();

  // stage Wk (hi/lo) into TW; WvT (plain bf16) into TSh
#pragma unroll
  for (int it = 0; it < 4; ++it) {
    int idx = it * 1024 + r * 4;
    int row = idx >> 6, c0 = idx & 63;
    float4 vw = *(const float4*)&Wk[ih * 4096 + idx];
    float fw[4] = {vw.x, vw.y, vw.z, vw.w};
    ushort4v wh, wl;
#pragma unroll
    for (int j = 0; j < 4; ++j) {
      unsigned short th, tl2;
      splitbf(fw[j], th, tl2);
      wh[j] = th; wl[j] = tl2;
    }
    *(ushort4v*)lp(TWh, row, c0 * 2) = wh;
    *(ushort4v*)lp(TWl, row, c0 * 2) = wl;
    float4 vv = *(const float4*)&Wv[ih * 4096 + idx];
    int q = row, d0 = c0;  // WvT[d][q] = Wv[q][d]
    *lp(TSh, d0 + 0, q * 2) = f2bf(vv.x);
    *lp(TSh, d0 + 1, q * 2) = f2bf(vv.y);
    *lp(TSh, d0 + 2, q * 2) = f2bf(vv.z);
    *lp(TSh, d0 + 3, q * 2) = f2bf(vv.w);
  }
  __syncthreads();
  {  // ks = Wk @ s_x
    int p = r >> 2, dc = (r & 3) * 16;
    float s = 0.f;
#pragma unroll
    for (int j = 0; j < 16; ++j) {
      int d = dc + j;
      s += (bf2f(*lp(TWh, p, d * 2)) + bf2f(*lp(TWl, p, d * 2))) * svec[d];
    }
    s += __shfl_xor(s, 1);
    s += __shfl_xor(s, 2);
    if ((r & 3) == 0) ksv[p] = s;
  }
  // phase 2: scores = A1 @ Wk^T (split-bf16)
  floatx4 a2[2][2] = {};
  {
    short8 Ah[2][2], Al[2][2], Bh[2][2], Bl[2][2];
#pragma unroll
    for (int mt = 0; mt < 2; ++mt)
#pragma unroll
      for (int ks = 0; ks < 2; ++ks) {
        Ah[mt][ks] = ldf(TAh, wm * 32 + mt * 16 + lm, ks * 64 + lk * 16);
        Al[mt][ks] = ldf(TAl, wm * 32 + mt * 16 + lm, ks * 64 + lk * 16);
        Bh[mt][ks] = ldf(TWh, wn * 32 + mt * 16 + lm, ks * 64 + lk * 16);
        Bl[mt][ks] = ldf(TWl, wn * 32 + mt * 16 + lm, ks * 64 + lk * 16);
      }
#pragma unroll
    for (int ks = 0; ks < 2; ++ks)
#pragma unroll
      for (int mt = 0; mt < 2; ++mt)
#pragma unroll
        for (int nt = 0; nt < 2; ++nt) {
          a2[mt][nt] = __builtin_amdgcn_mfma_f32_16x16x32_bf16(Ah[mt][ks], Bh[nt][ks], a2[mt][nt], 0, 0, 0);
          a2[mt][nt] = __builtin_amdgcn_mfma_f32_16x16x32_bf16(Ah[mt][ks], Bl[nt][ks], a2[mt][nt], 0, 0, 0);
          a2[mt][nt] = __builtin_amdgcn_mfma_f32_16x16x32_bf16(Al[mt][ks], Bh[nt][ks], a2[mt][nt], 0, 0, 0);
        }
  }
  __syncthreads();
#pragma unroll
  for (int mt = 0; mt < 2; ++mt)
#pragma unroll
    for (int nt = 0; nt < 2; ++nt)
#pragma unroll
      for (int q = 0; q < 4; ++q) {
        int p = wm * 32 + mt * 16 + lk * 4 + q;
        int qq = wn * 32 + nt * 16 + lm;
        float v = a2[mt][nt][q] + qsv[p] * bkv[qq] + bqv[p] * ksv[qq] +
                  1024.f * bqv[p] * bkv[qq];
        SC[p * 68 + qq] = v * 0.125f;
      }
  __syncthreads();
  {  // wave-parallel softmax (4 lanes/row) -> w bf16 into TSl; c -> global
    int p = r >> 2, qc = (r & 3) * 16;
    float e[16];
    float m = -1e30f;
#pragma unroll
    for (int j = 0; j < 16; ++j) {
      e[j] = SC[p * 68 + qc + j];
      m = fmaxf(m, e[j]);
    }
    m = fmaxf(m, __shfl_xor(m, 1));
    m = fmaxf(m, __shfl_xor(m, 2));
    float s = 0.f, cp = 0.f;
#pragma unroll
    for (int j = 0; j < 16; ++j) {
      float ex = __expf(e[j] - m);
      e[j] = ex;
      s += ex;
      cp += ex * bvv[qc + j];
    }
    s += __shfl_xor(s, 1);
    s += __shfl_xor(s, 2);
    cp += __shfl_xor(cp, 1);
    cp += __shfl_xor(cp, 2);
    float inv = 1.f / s;
#pragma unroll
    for (int j = 0; j < 16; ++j) *lp(TSl, p, (qc + j) * 2) = f2bf(e[j] * inv);
    if ((r & 3) == 0)
      Mtbf[(size_t)(2048 + bh) * 1024 + ih * 64 + p] = f2bf(cp * inv);
  }
  __syncthreads();
  // phase 3: M^T = WvT x w (plain bf16)
  floatx4 a3[2][2] = {};
  {
    short8 A3[2][2], B3[2][2];
#pragma unroll
    for (int mt = 0; mt < 2; ++mt)
#pragma unroll
      for (int ks = 0; ks < 2; ++ks) {
        A3[mt][ks] = ldf(TSh, wm * 32 + mt * 16 + lm, ks * 64 + lk * 16);
        B3[mt][ks] = ldf(TSl, wn * 32 + mt * 16 + lm, ks * 64 + lk * 16);
      }
#pragma unroll
    for (int ks = 0; ks < 2; ++ks)
#pragma unroll
      for (int mt = 0; mt < 2; ++mt)
#pragma unroll
        for (int nt = 0; nt < 2; ++nt)
          a3[mt][nt] = __builtin_amdgcn_mfma_f32_16x16x32_bf16(A3[mt][ks], B3[nt][ks], a3[mt][nt], 0, 0, 0);
  }
#pragma unroll
  for (int mt = 0; mt < 2; ++mt)
#pragma unroll
    for (int nt = 0; nt < 2; ++nt)
#pragma unroll
      for (int q = 0; q < 4; ++q) {
        int d = wm * 32 + mt * 16 + lk * 4 + q;
        int p = wn * 32 + nt * 16 + lm;
        Mtbf[(size_t)(bh * 64 + d) * 1024 + ih * 64 + p] = f2bf(a3[mt][nt][q]);
      }
}

// ---------------------------------------------------------------------------
// Kernel C-fused (MFMA) — round-10 structure; Wf read directly as fp32 and
// converted in-register (Wfbf eliminated). block = (fx, bh), 1 blk/CU.
// ---------------------------------------------------------------------------
__global__ __launch_bounds__(256) void kC(const unsigned short* __restrict__ xbf,
                                          const float* __restrict__ Wf,
                                          const unsigned short* __restrict__ Mtbf,
                                          const float* __restrict__ bfv,
                                          float* __restrict__ out) {
  const int fx = blockIdx.x, bh = blockIdx.y;
  const int f0 = fx * 128;
  const int r = threadIdx.x;
  const int w = r >> 6, l = r & 63;
  const int lm = l & 15, lk = l >> 4;

  __shared__ __align__(16) unsigned short GT[128 * 64];  // 16 KB, swizzled rows
  __shared__ __align__(16) unsigned short cL[1024];      // 2 KB
  __shared__ float gL[128];                              // 512 B

  // stage c (Mt row 2048+bh)
  if (r < 128)
    *reinterpret_cast<ushort8v*>(&cL[r * 8]) = *reinterpret_cast<const ushort8v*>(
        &Mtbf[(size_t)(2048 + bh) * 1024 + r * 8]);
  __syncthreads();

  // ---- G-step: G[f][d] = sum_e Wf[f][e] * M[e][d]; g[f] = Wf@c + bf
  {
    const int wf = w >> 1, wd = w & 1;  // f-half (64), d-half (32)
    const float* ap = Wf + (size_t)(f0 + wf * 64 + lm) * 1024 + lk * 8;
    const unsigned short* bp = Mtbf + (size_t)(bh * 64 + wd * 32 + lm) * 1024 + lk * 8;
    floatx4 acc[4][2] = {};
    floatx4 gacc[4] = {};
    for (int k0 = 0; k0 < 1024; k0 += 64) {
      short8 a[4][2], b[2][2], cf[2];
#pragma unroll
      for (int mi = 0; mi < 4; ++mi)
#pragma unroll
        for (int ks = 0; ks < 2; ++ks)
          a[mi][ks] = ldwf(ap + mi * 16 * 1024 + k0 + ks * 32);
#pragma unroll
      for (int ni = 0; ni < 2; ++ni)
#pragma unroll
        for (int ks = 0; ks < 2; ++ks)
          b[ni][ks] = *reinterpret_cast<const short8*>(bp + ni * 16 * 1024 + k0 + ks * 32);
#pragma unroll
      for (int ks = 0; ks < 2; ++ks)
        cf[ks] = *reinterpret_cast<const short8*>(&cL[k0 + ks * 32 + lk * 8]);
#pragma unroll
      for (int ks = 0; ks < 2; ++ks)
#pragma unroll
        for (int mi = 0; mi < 4; ++mi) {
#pragma unroll
          for (int ni = 0; ni < 2; ++ni)
            acc[mi][ni] = __builtin_amdgcn_mfma_f32_16x16x32_bf16(
                a[mi][ks], b[ni][ks], acc[mi][ni], 0, 0, 0);
          if (wd == 0)  // g rider: B columns all = c -> every output col = Wf@c
            gacc[mi] = __builtin_amdgcn_mfma_f32_16x16x32_bf16(
                a[mi][ks], cf[ks], gacc[mi], 0, 0, 0);
        }
    }
    // write G quadrant to LDS (swizzled [f_local][d*2])
#pragma unroll
    for (int mi = 0; mi < 4; ++mi)
#pragma unroll
      for (int ni = 0; ni < 2; ++ni)
#pragma unroll
        for (int q = 0; q < 4; ++q) {
          int fl = wf * 64 + mi * 16 + lk * 4 + q;
          int d = wd * 32 + ni * 16 + lm;
          *lp(GT, fl, d * 2) = f2bf(acc[mi][ni][q]);
        }
    if (wd == 0 && lm == 0) {
#pragma unroll
      for (int mi = 0; mi < 4; ++mi)
#pragma unroll
        for (int q = 0; q < 4; ++q) {
          int fl = wf * 64 + mi * 16 + lk * 4 + q;
          gL[fl] = gacc[mi][q] + bfv[f0 + fl];
        }
    }
  }
  __syncthreads();

  // ---- t-loop: out[t][f] = sum_d x[t][d] * G[f][d] + g[f]
  const int wt = w >> 1, wc = w & 1;  // t-quad (64), f-quad (64)
  float gv[4];
#pragma unroll
  for (int ni = 0; ni < 4; ++ni) gv[ni] = gL[wc * 64 + ni * 16 + lm];
  short8 bfr[4][2];
#pragma unroll
  for (int ni = 0; ni < 4; ++ni)
#pragma unroll
    for (int ks = 0; ks < 2; ++ks)
      bfr[ni][ks] = ldf(GT, wc * 64 + ni * 16 + lm, (ks * 32 + lk * 8) * 2);
  float* ob = out + (size_t)bh * 1048576;
  for (int t0 = 0; t0 < 1024; t0 += 128) {
    const unsigned short* ap =
        xbf + (size_t)bh * 65536 + (size_t)(t0 + wt * 64 + lm) * 64 + lk * 8;
    short8 a[4][2];
#pragma unroll
    for (int mi = 0; mi < 4; ++mi)
#pragma unroll
      for (int ks = 0; ks < 2; ++ks)
        a[mi][ks] = *reinterpret_cast<const short8*>(ap + mi * 16 * 64 + ks * 32);
    floatx4 acc[4][4] = {};
#pragma unroll
    for (int ks = 0; ks < 2; ++ks)
#pragma unroll
      for (int mi = 0; mi < 4; ++mi)
#pragma unroll
        for (int ni = 0; ni < 4; ++ni)
          acc[mi][ni] = __builtin_amdgcn_mfma_f32_16x16x32_bf16(
              a[mi][ks], bfr[ni][ks], acc[mi][ni], 0, 0, 0);
#pragma unroll
    for (int mi = 0; mi < 4; ++mi)
#pragma unroll
      for (int ni = 0; ni < 4; ++ni) {
        const int f = f0 + wc * 64 + ni * 16 + lm;
#pragma unroll
        for (int q = 0; q < 4; ++q) {
          const int t = t0 + wt * 64 + mi * 16 + lk * 4 + q;
          ob[(size_t)t * 1024 + f] = acc[mi][ni][q] + gv[ni];
        }
      }
  }
}

extern "C" void kernel_launch(void* const* d_in, const int* in_sizes, int n_in,
                              void* d_out, int out_size, void* d_ws, size_t ws_size,
                              hipStream_t stream) {
  const float* x = (const float*)d_in[0];
  const float* Wq = (const float*)d_in[1];
  const float* bq = (const float*)d_in[2];
  const float* Wk = (const float*)d_in[3];
  const float* bk = (const float*)d_in[4];
  const float* Wv = (const float*)d_in[5];
  const float* bv = (const float*)d_in[6];
  const float* Wf = (const float*)d_in[7];
  const float* bf = (const float*)d_in[8];
  float* out = (float*)d_out;

  float* ws = (float*)d_ws;
  unsigned short* xbf = (unsigned short*)ws;          // 2097152 us
  unsigned short* Mtbf = xbf + 2097152;               // 2162688 us

  kB1<<<512, 256, 0, stream>>>(x, Wq, bq, Wk, bk, Wv, bv, Mtbf, xbf);
  kC<<<dim3(8, 32), 256, 0, stream>>>(xbf, Wf, Mtbf, bf, out);
}

// Round 18
// 79.751 us; speedup vs baseline: 1.4948x; 1.4948x over previous
//
#include <hip/hip_runtime.h>

// Problem constants: B=2, T=1024, E=1024, H=16, D=64
#define TT 1024
#define EE 1024

typedef __attribute__((ext_vector_type(8))) short short8;      // 8 bf16 MFMA frag
typedef __attribute__((ext_vector_type(4))) float floatx4;     // MFMA acc
typedef __attribute__((ext_vector_type(4))) unsigned short ushort4v;
typedef __attribute__((ext_vector_type(8))) unsigned short ushort8v;

static __device__ __forceinline__ unsigned short f2bf(float f) {
  union { float f; unsigned int u; } v; v.f = f;
  unsigned int u = v.u;
  u += 0x7FFFu + ((u >> 16) & 1u);  // RNE
  return (unsigned short)(u >> 16);
}
static __device__ __forceinline__ float bf2f(unsigned short u) {
  union { unsigned int i; float f; } v; v.i = ((unsigned int)u) << 16;
  return v.f;
}
static __device__ __forceinline__ void splitbf(float x, unsigned short& h,
                                               unsigned short& l) {
  h = f2bf(x);
  l = f2bf(x - bf2f(h));
}
// swizzled LDS access into a [rows][128B] bf16 tile, XOR bits 4-6 by row&7
static __device__ __forceinline__ unsigned short* lp(const unsigned short* t,
                                                     int row, int byte) {
  return (unsigned short*)((const char*)t + row * 128 + (byte ^ ((row & 7) << 4)));
}
static __device__ __forceinline__ short8 ldf(const unsigned short* t, int row,
                                             int byte) {
  return *(const short8*)((const char*)t + row * 128 + (byte ^ ((row & 7) << 4)));
}

// ---------------------------------------------------------------------------
// Kernel P (fused prep, 512 blocks):
//  blocks 0-255  : per (bh, t-chunk of 128): Sxx_part / sx_part + xbf emit.
//  blocks 256-511: Wf fp32 -> bf16.
// ---------------------------------------------------------------------------
__global__ __launch_bounds__(256) void kP(const float* __restrict__ x,
                                          const float* __restrict__ Wf,
                                          float* __restrict__ Sxx_part,
                                          float* __restrict__ sx_part,
                                          unsigned short* __restrict__ Wfbf,
                                          unsigned short* __restrict__ xbf) {
  const int bx = blockIdx.x;
  const int r = threadIdx.x;
  if (bx >= 256) {
    const int wb = bx - 256;
#pragma unroll
    for (int it = 0; it < 4; ++it) {
      int idx = wb * 4096 + it * 1024 + r * 4;
      float4 v = *reinterpret_cast<const float4*>(&Wf[idx]);
      ushort4v o;
      o[0] = f2bf(v.x); o[1] = f2bf(v.y); o[2] = f2bf(v.z); o[3] = f2bf(v.w);
      *reinterpret_cast<ushort4v*>(&Wfbf[idx]) = o;
    }
    return;
  }
  const int bh = bx >> 3, chunk = bx & 7;
  const int b = bh >> 4, h = bh & 15;
  const int t0 = chunk * 128;
  __shared__ float Xs[128 * 64];  // 32 KB
  const float* xb = x + ((size_t)b * TT + t0) * EE + h * 64;
#pragma unroll
  for (int j = 0; j < 8; ++j) {
    int idx4 = j * 256 + r;
    int t = idx4 >> 4, c4 = idx4 & 15;
    *reinterpret_cast<float4*>(&Xs[t * 64 + c4 * 4]) =
        *reinterpret_cast<const float4*>(&xb[(size_t)t * EE + c4 * 4]);
  }
  __syncthreads();
#pragma unroll
  for (int j = 0; j < 4; ++j) {
    int idx8 = j * 256 + r;
    int t = idx8 >> 3, gch = idx8 & 7;
    ushort8v o;
#pragma unroll
    for (int e = 0; e < 8; ++e) o[e] = f2bf(Xs[t * 64 + gch * 8 + e]);
    *reinterpret_cast<ushort8v*>(&xbf[((size_t)bh * TT + t0 + t) * 64 + gch * 8]) = o;
  }
  const int p0 = (r >> 4) * 4, q0 = (r & 15) * 4;
  float acc[4][4] = {};
  for (int t = 0; t < 128; ++t) {
    float4 pv = *reinterpret_cast<const float4*>(&Xs[t * 64 + p0]);
    float4 qv = *reinterpret_cast<const float4*>(&Xs[t * 64 + q0]);
    float pa[4] = {pv.x, pv.y, pv.z, pv.w};
    float qa[4] = {qv.x, qv.y, qv.z, qv.w};
#pragma unroll
    for (int i = 0; i < 4; ++i)
#pragma unroll
      for (int j = 0; j < 4; ++j) acc[i][j] += pa[i] * qa[j];
  }
  float* Sb = Sxx_part + ((size_t)chunk * 32 + bh) * 4096;
#pragma unroll
  for (int i = 0; i < 4; ++i) {
    float4 v = make_float4(acc[i][0], acc[i][1], acc[i][2], acc[i][3]);
    *reinterpret_cast<float4*>(&Sb[(p0 + i) * 64 + q0]) = v;
  }
  if (r < 64) {
    float s = 0.f;
    for (int t = 0; t < 128; ++t) s += Xs[t * 64 + r];
    sx_part[(chunk * 32 + bh) * 64 + r] = s;
  }
}

// ---------------------------------------------------------------------------
// Kernel B1 (MFMA) — XCD-aware decode (bh = blk&31, ih = blk>>5): the 16
// same-bh blocks (which re-read the same 128 KB of Sxx_part) land on the
// same XCD L2.
// ---------------------------------------------------------------------------
__global__ __launch_bounds__(256) void kB1(const float* __restrict__ Sxx_part,
                                           const float* __restrict__ sx_part,
                                           const float* __restrict__ Wq,
                                           const float* __restrict__ bq,
                                           const float* __restrict__ Wk,
                                           const float* __restrict__ bk,
                                           const float* __restrict__ Wv,
                                           const float* __restrict__ bv,
                                           unsigned short* __restrict__ Mtbf) {
  const int blk = blockIdx.x;
  const int bh = blk & 31, ih = blk >> 5;  // XCD-locality remap
  const int r = threadIdx.x;
  const int w = r >> 6, l = r & 63;
  const int wm = w >> 1, wn = w & 1;
  const int lm = l & 15, lk = l >> 4;

  __shared__ unsigned short TSh[4096], TSl[4096];  // S hi/lo -> WvT, w
  __shared__ unsigned short TWh[4096], TWl[4096];  // Wq -> Wk (hi/lo)
  __shared__ unsigned short TAh[4096], TAl[4096];  // A1 hi/lo
  __shared__ float SC[64 * 68];                    // fp32 scores
  __shared__ float svec[64], qsv[64], ksv[64], bqv[64], bkv[64], bvv[64];

#pragma unroll
  for (int it = 0; it < 4; ++it) {
    int idx = it * 1024 + r * 4;
    int row = idx >> 6, c0 = idx & 63;
    float4 vs = *(const float4*)&Sxx_part[(size_t)bh * 4096 + idx];
#pragma unroll
    for (int ch = 1; ch < 8; ++ch) {
      float4 tv = *(const float4*)&Sxx_part[((size_t)ch * 32 + bh) * 4096 + idx];
      vs.x += tv.x; vs.y += tv.y; vs.z += tv.z; vs.w += tv.w;
    }
    float4 vw = *(const float4*)&Wq[ih * 4096 + idx];
    float fs[4] = {vs.x, vs.y, vs.z, vs.w};
    float fw[4] = {vw.x, vw.y, vw.z, vw.w};
    ushort4v sh, sl, wh, wl;
#pragma unroll
    for (int j = 0; j < 4; ++j) {
      unsigned short th, tl;
      splitbf(fs[j], th, tl);
      sh[j] = th; sl[j] = tl;
      splitbf(fw[j], th, tl);
      wh[j] = th; wl[j] = tl;
    }
    *(ushort4v*)lp(TSh, row, c0 * 2) = sh;
    *(ushort4v*)lp(TSl, row, c0 * 2) = sl;
    *(ushort4v*)lp(TWh, row, c0 * 2) = wh;
    *(ushort4v*)lp(TWl, row, c0 * 2) = wl;
  }
  if (r < 64) {
    float s = 0.f;
#pragma unroll
    for (int ch = 0; ch < 8; ++ch) s += sx_part[(ch * 32 + bh) * 64 + r];
    svec[r] = s;
    bqv[r] = bq[ih * 64 + r];
    bkv[r] = bk[ih * 64 + r];
    bvv[r] = bv[ih * 64 + r];
  }
  __syncthreads();

  // phase 1: A1 = Wq @ S (split-bf16)
  floatx4 a1[2][2] = {};
  {
    short8 Ah[2][2], Al[2][2], Bh[2][2], Bl[2][2];
#pragma unroll
    for (int mt = 0; mt < 2; ++mt)
#pragma unroll
      for (int ks = 0; ks < 2; ++ks) {
        Ah[mt][ks] = ldf(TWh, wm * 32 + mt * 16 + lm, ks * 64 + lk * 16);
        Al[mt][ks] = ldf(TWl, wm * 32 + mt * 16 + lm, ks * 64 + lk * 16);
        Bh[mt][ks] = ldf(TSh, wn * 32 + mt * 16 + lm, ks * 64 + lk * 16);
        Bl[mt][ks] = ldf(TSl, wn * 32 + mt * 16 + lm, ks * 64 + lk * 16);
      }
#pragma unroll
    for (int ks = 0; ks < 2; ++ks)
#pragma unroll
      for (int mt = 0; mt < 2; ++mt)
#pragma unroll
        for (int nt = 0; nt < 2; ++nt) {
          a1[mt][nt] = __builtin_amdgcn_mfma_f32_16x16x32_bf16(Ah[mt][ks], Bh[nt][ks], a1[mt][nt], 0, 0, 0);
          a1[mt][nt] = __builtin_amdgcn_mfma_f32_16x16x32_bf16(Ah[mt][ks], Bl[nt][ks], a1[mt][nt], 0, 0, 0);
          a1[mt][nt] = __builtin_amdgcn_mfma_f32_16x16x32_bf16(Al[mt][ks], Bh[nt][ks], a1[mt][nt], 0, 0, 0);
        }
  }
#pragma unroll
  for (int mt = 0; mt < 2; ++mt)
#pragma unroll
    for (int nt = 0; nt < 2; ++nt)
#pragma unroll
      for (int q = 0; q < 4; ++q) {
        int p = wm * 32 + mt * 16 + lk * 4 + q;
        int dd = wn * 32 + nt * 16 + lm;
        unsigned short h, lo2;
        splitbf(a1[mt][nt][q], h, lo2);
        *lp(TAh, p, dd * 2) = h;
        *lp(TAl, p, dd * 2) = lo2;
      }
  {  // qs = Wq @ s_x
    int p = r >> 2, dc = (r & 3) * 16;
    float s = 0.f;
#pragma unroll
    for (int j = 0; j < 16; ++j) {
      int d = dc + j;
      s += (bf2f(*lp(TWh, p, d * 2)) + bf2f(*lp(TWl, p, d * 2))) * svec[d];
    }
    s += __shfl_xor(s, 1);
    s += __shfl_xor(s, 2);
    if ((r & 3) == 0) qsv[p] = s;
  }
  __syncthreads();

  // stage Wk (hi/lo) into TW; WvT (plain bf16) into TSh
#pragma unroll
  for (int it = 0; it < 4; ++it) {
    int idx = it * 1024 + r * 4;
    int row = idx >> 6, c0 = idx & 63;
    float4 vw = *(const float4*)&Wk[ih * 4096 + idx];
    float fw[4] = {vw.x, vw.y, vw.z, vw.w};
    ushort4v wh, wl;
#pragma unroll
    for (int j = 0; j < 4; ++j) {
      unsigned short th, tl;
      splitbf(fw[j], th, tl);
      wh[j] = th; wl[j] = tl;
    }
    *(ushort4v*)lp(TWh, row, c0 * 2) = wh;
    *(ushort4v*)lp(TWl, row, c0 * 2) = wl;
    float4 vv = *(const float4*)&Wv[ih * 4096 + idx];
    int q = row, d0 = c0;  // WvT[d][q] = Wv[q][d]
    *lp(TSh, d0 + 0, q * 2) = f2bf(vv.x);
    *lp(TSh, d0 + 1, q * 2) = f2bf(vv.y);
    *lp(TSh, d0 + 2, q * 2) = f2bf(vv.z);
    *lp(TSh, d0 + 3, q * 2) = f2bf(vv.w);
  }
  __syncthreads();
  {  // ks = Wk @ s_x
    int p = r >> 2, dc = (r & 3) * 16;
    float s = 0.f;
#pragma unroll
    for (int j = 0; j < 16; ++j) {
      int d = dc + j;
      s += (bf2f(*lp(TWh, p, d * 2)) + bf2f(*lp(TWl, p, d * 2))) * svec[d];
    }
    s += __shfl_xor(s, 1);
    s += __shfl_xor(s, 2);
    if ((r & 3) == 0) ksv[p] = s;
  }
  // phase 2: scores = A1 @ Wk^T (split-bf16)
  floatx4 a2[2][2] = {};
  {
    short8 Ah[2][2], Al[2][2], Bh[2][2], Bl[2][2];
#pragma unroll
    for (int mt = 0; mt < 2; ++mt)
#pragma unroll
      for (int ks = 0; ks < 2; ++ks) {
        Ah[mt][ks] = ldf(TAh, wm * 32 + mt * 16 + lm, ks * 64 + lk * 16);
        Al[mt][ks] = ldf(TAl, wm * 32 + mt * 16 + lm, ks * 64 + lk * 16);
        Bh[mt][ks] = ldf(TWh, wn * 32 + mt * 16 + lm, ks * 64 + lk * 16);
        Bl[mt][ks] = ldf(TWl, wn * 32 + mt * 16 + lm, ks * 64 + lk * 16);
      }
#pragma unroll
    for (int ks = 0; ks < 2; ++ks)
#pragma unroll
      for (int mt = 0; mt < 2; ++mt)
#pragma unroll
        for (int nt = 0; nt < 2; ++nt) {
          a2[mt][nt] = __builtin_amdgcn_mfma_f32_16x16x32_bf16(Ah[mt][ks], Bh[nt][ks], a2[mt][nt], 0, 0, 0);
          a2[mt][nt] = __builtin_amdgcn_mfma_f32_16x16x32_bf16(Ah[mt][ks], Bl[nt][ks], a2[mt][nt], 0, 0, 0);
          a2[mt][nt] = __builtin_amdgcn_mfma_f32_16x16x32_bf16(Al[mt][ks], Bh[nt][ks], a2[mt][nt], 0, 0, 0);
        }
  }
  __syncthreads();
#pragma unroll
  for (int mt = 0; mt < 2; ++mt)
#pragma unroll
    for (int nt = 0; nt < 2; ++nt)
#pragma unroll
      for (int q = 0; q < 4; ++q) {
        int p = wm * 32 + mt * 16 + lk * 4 + q;
        int qq = wn * 32 + nt * 16 + lm;
        float v = a2[mt][nt][q] + qsv[p] * bkv[qq] + bqv[p] * ksv[qq] +
                  1024.f * bqv[p] * bkv[qq];
        SC[p * 68 + qq] = v * 0.125f;
      }
  __syncthreads();
  {  // wave-parallel softmax (4 lanes/row) -> w bf16 into TSl; c -> global
    int p = r >> 2, qc = (r & 3) * 16;
    float e[16];
    float m = -1e30f;
#pragma unroll
    for (int j = 0; j < 16; ++j) {
      e[j] = SC[p * 68 + qc + j];
      m = fmaxf(m, e[j]);
    }
    m = fmaxf(m, __shfl_xor(m, 1));
    m = fmaxf(m, __shfl_xor(m, 2));
    float s = 0.f, cp = 0.f;
#pragma unroll
    for (int j = 0; j < 16; ++j) {
      float ex = __expf(e[j] - m);
      e[j] = ex;
      s += ex;
      cp += ex * bvv[qc + j];
    }
    s += __shfl_xor(s, 1);
    s += __shfl_xor(s, 2);
    cp += __shfl_xor(cp, 1);
    cp += __shfl_xor(cp, 2);
    float inv = 1.f / s;
#pragma unroll
    for (int j = 0; j < 16; ++j) *lp(TSl, p, (qc + j) * 2) = f2bf(e[j] * inv);
    if ((r & 3) == 0)
      Mtbf[(size_t)(2048 + bh) * 1024 + ih * 64 + p] = f2bf(cp * inv);
  }
  __syncthreads();
  // phase 3: M^T = WvT x w (plain bf16)
  floatx4 a3[2][2] = {};
  {
    short8 A3[2][2], B3[2][2];
#pragma unroll
    for (int mt = 0; mt < 2; ++mt)
#pragma unroll
      for (int ks = 0; ks < 2; ++ks) {
        A3[mt][ks] = ldf(TSh, wm * 32 + mt * 16 + lm, ks * 64 + lk * 16);
        B3[mt][ks] = ldf(TSl, wn * 32 + mt * 16 + lm, ks * 64 + lk * 16);
      }
#pragma unroll
    for (int ks = 0; ks < 2; ++ks)
#pragma unroll
      for (int mt = 0; mt < 2; ++mt)
#pragma unroll
        for (int nt = 0; nt < 2; ++nt)
          a3[mt][nt] = __builtin_amdgcn_mfma_f32_16x16x32_bf16(A3[mt][ks], B3[nt][ks], a3[mt][nt], 0, 0, 0);
  }
#pragma unroll
  for (int mt = 0; mt < 2; ++mt)
#pragma unroll
    for (int nt = 0; nt < 2; ++nt)
#pragma unroll
      for (int q = 0; q < 4; ++q) {
        int d = wm * 32 + mt * 16 + lk * 4 + q;
        int p = wn * 32 + nt * 16 + lm;
        Mtbf[(size_t)(bh * 64 + d) * 1024 + ih * 64 + p] = f2bf(a3[mt][nt][q]);
      }
}

// ---------------------------------------------------------------------------
// Kernel C-fused (MFMA) — block = (fx, bh), 1 blk/CU: G-step (= old kB2
// partition) + g rider into LDS, then 8 t-tiles of out = x G^T + g.
// ---------------------------------------------------------------------------
__global__ __launch_bounds__(256) void kC(const unsigned short* __restrict__ xbf,
                                          const unsigned short* __restrict__ Wfbf,
                                          const unsigned short* __restrict__ Mtbf,
                                          const float* __restrict__ bfv,
                                          float* __restrict__ out) {
  const int fx = blockIdx.x, bh = blockIdx.y;
  const int f0 = fx * 128;
  const int r = threadIdx.x;
  const int w = r >> 6, l = r & 63;
  const int lm = l & 15, lk = l >> 4;

  __shared__ __align__(16) unsigned short GT[128 * 64];  // 16 KB, swizzled rows
  __shared__ __align__(16) unsigned short cL[1024];      // 2 KB
  __shared__ float gL[128];                              // 512 B

  // stage c (Mt row 2048+bh)
  if (r < 128)
    *reinterpret_cast<ushort8v*>(&cL[r * 8]) = *reinterpret_cast<const ushort8v*>(
        &Mtbf[(size_t)(2048 + bh) * 1024 + r * 8]);
  __syncthreads();

  // ---- G-step: G[f][d] = sum_e Wf[f][e] * M[e][d]; g[f] = Wf@c + bf
  {
    const int wf = w >> 1, wd = w & 1;  // f-half (64), d-half (32)
    const unsigned short* ap = Wfbf + (size_t)(f0 + wf * 64 + lm) * 1024 + lk * 8;
    const unsigned short* bp = Mtbf + (size_t)(bh * 64 + wd * 32 + lm) * 1024 + lk * 8;
    floatx4 acc[4][2] = {};
    floatx4 gacc[4] = {};
    for (int k0 = 0; k0 < 1024; k0 += 64) {
      short8 a[4][2], b[2][2], cf[2];
#pragma unroll
      for (int mi = 0; mi < 4; ++mi)
#pragma unroll
        for (int ks = 0; ks < 2; ++ks)
          a[mi][ks] = *reinterpret_cast<const short8*>(ap + mi * 16 * 1024 + k0 + ks * 32);
#pragma unroll
      for (int ni = 0; ni < 2; ++ni)
#pragma unroll
        for (int ks = 0; ks < 2; ++ks)
          b[ni][ks] = *reinterpret_cast<const short8*>(bp + ni * 16 * 1024 + k0 + ks * 32);
#pragma unroll
      for (int ks = 0; ks < 2; ++ks)
        cf[ks] = *reinterpret_cast<const short8*>(&cL[k0 + ks * 32 + lk * 8]);
#pragma unroll
      for (int ks = 0; ks < 2; ++ks)
#pragma unroll
        for (int mi = 0; mi < 4; ++mi) {
#pragma unroll
          for (int ni = 0; ni < 2; ++ni)
            acc[mi][ni] = __builtin_amdgcn_mfma_f32_16x16x32_bf16(
                a[mi][ks], b[ni][ks], acc[mi][ni], 0, 0, 0);
          if (wd == 0)  // g rider: B columns all = c -> every output col = Wf@c
            gacc[mi] = __builtin_amdgcn_mfma_f32_16x16x32_bf16(
                a[mi][ks], cf[ks], gacc[mi], 0, 0, 0);
        }
    }
    // write G quadrant to LDS (swizzled [f_local][d*2])
#pragma unroll
    for (int mi = 0; mi < 4; ++mi)
#pragma unroll
      for (int ni = 0; ni < 2; ++ni)
#pragma unroll
        for (int q = 0; q < 4; ++q) {
          int fl = wf * 64 + mi * 16 + lk * 4 + q;
          int d = wd * 32 + ni * 16 + lm;
          *lp(GT, fl, d * 2) = f2bf(acc[mi][ni][q]);
        }
    if (wd == 0 && lm == 0) {
#pragma unroll
      for (int mi = 0; mi < 4; ++mi)
#pragma unroll
        for (int q = 0; q < 4; ++q) {
          int fl = wf * 64 + mi * 16 + lk * 4 + q;
          gL[fl] = gacc[mi][q] + bfv[f0 + fl];
        }
    }
  }
  __syncthreads();

  // ---- t-loop: out[t][f] = sum_d x[t][d] * G[f][d] + g[f]
  const int wt = w >> 1, wc = w & 1;  // t-quad (64), f-quad (64)
  float gv[4];
#pragma unroll
  for (int ni = 0; ni < 4; ++ni) gv[ni] = gL[wc * 64 + ni * 16 + lm];
  short8 bfr[4][2];
#pragma unroll
  for (int ni = 0; ni < 4; ++ni)
#pragma unroll
    for (int ks = 0; ks < 2; ++ks)
      bfr[ni][ks] = ldf(GT, wc * 64 + ni * 16 + lm, (ks * 32 + lk * 8) * 2);
  float* ob = out + (size_t)bh * 1048576;
  for (int t0 = 0; t0 < 1024; t0 += 128) {
    const unsigned short* ap =
        xbf + (size_t)bh * 65536 + (size_t)(t0 + wt * 64 + lm) * 64 + lk * 8;
    short8 a[4][2];
#pragma unroll
    for (int mi = 0; mi < 4; ++mi)
#pragma unroll
      for (int ks = 0; ks < 2; ++ks)
        a[mi][ks] = *reinterpret_cast<const short8*>(ap + mi * 16 * 64 + ks * 32);
    floatx4 acc[4][4] = {};
#pragma unroll
    for (int ks = 0; ks < 2; ++ks)
#pragma unroll
      for (int mi = 0; mi < 4; ++mi)
#pragma unroll
        for (int ni = 0; ni < 4; ++ni)
          acc[mi][ni] = __builtin_amdgcn_mfma_f32_16x16x32_bf16(
              a[mi][ks], bfr[ni][ks], acc[mi][ni], 0, 0, 0);
#pragma unroll
    for (int mi = 0; mi < 4; ++mi)
#pragma unroll
      for (int ni = 0; ni < 4; ++ni) {
        const int f = f0 + wc * 64 + ni * 16 + lm;
#pragma unroll
        for (int q = 0; q < 4; ++q) {
          const int t = t0 + wt * 64 + mi * 16 + lk * 4 + q;
          ob[(size_t)t * 1024 + f] = acc[mi][ni][q] + gv[ni];
        }
      }
  }
}

extern "C" void kernel_launch(void* const* d_in, const int* in_sizes, int n_in,
                              void* d_out, int out_size, void* d_ws, size_t ws_size,
                              hipStream_t stream) {
  const float* x = (const float*)d_in[0];
  const float* Wq = (const float*)d_in[1];
  const float* bq = (const float*)d_in[2];
  const float* Wk = (const float*)d_in[3];
  const float* bk = (const float*)d_in[4];
  const float* Wv = (const float*)d_in[5];
  const float* bv = (const float*)d_in[6];
  const float* Wf = (const float*)d_in[7];
  const float* bf = (const float*)d_in[8];
  float* out = (float*)d_out;

  float* ws = (float*)d_ws;
  float* Sxx_part = ws;                               // 8*32*4096 = 1048576 f
  float* sx_part = Sxx_part + 1048576;                // 16384 f
  unsigned short* Wfbf = (unsigned short*)(sx_part + 16384);  // 1048576 us
  unsigned short* xbf = Wfbf + 1048576;               // 2097152 us
  unsigned short* Mtbf = xbf + 2097152;               // 2162688 us

  kP<<<512, 256, 0, stream>>>(x, Wf, Sxx_part, sx_part, Wfbf, xbf);
  kB1<<<512, 256, 0, stream>>>(Sxx_part, sx_part, Wq, bq, Wk, bk, Wv, bv, Mtbf);
  kC<<<dim3(8, 32), 256, 0, stream>>>(xbf, Wfbf, Mtbf, bf, out);
}